// Round 3
// baseline (44.014 us; speedup 1.0000x reference)
//
#include <hip/hip_runtime.h>
#include <hip/hip_bf16.h>

// Quantum layer: 4 qubits, 2 layers. Everything after the RY(x) encoding is a
// fixed unitary U (weights are batch-constant). evs_q(x) = s^T Re(M_q) s with
// s the real product state from RY encoding; since v v^T spans (1,cos t,sin t)
// per qubit, evs_q is multilinear with 81 coefficients per output.
// qsetup (4 blocks) computes C[4][81] from weights into d_ws.
// qmain: coefficients staged in LDS (broadcast ds_read), EPT=2 elements
// interleaved inside the coefficient loop so each load feeds both elements.

__global__ __launch_bounds__(256) void qsetup(const float* __restrict__ w,
                                              float* __restrict__ C) {
    __shared__ float Ur[16][16];   // [row k][col j]
    __shared__ float Ui[16][16];
    __shared__ float M[16][16];
    const int q = blockIdx.x;      // output qubit 0..3
    const int tid = threadIdx.x;

    // ---- step 1: threads 0..15 each simulate one basis column of U ----
    if (tid < 16) {
        float re[16], im[16];
#pragma unroll
        for (int i = 0; i < 16; ++i) { re[i] = (i == tid) ? 1.0f : 0.0f; im[i] = 0.0f; }

#pragma unroll
        for (int ly = 0; ly < 2; ++ly) {
#pragma unroll
            for (int qq = 0; qq < 4; ++qq) {
                const int mm = 8 >> qq;
                float th, c, s;
                // RX(w[ly][qq][0])
                th = w[(ly * 4 + qq) * 3 + 0] * 0.5f; c = __cosf(th); s = __sinf(th);
#pragma unroll
                for (int i = 0; i < 16; ++i) if (!(i & mm)) {
                    const int j = i | mm;
                    float r0 = re[i], i0 = im[i], r1 = re[j], i1 = im[j];
                    re[i] = c * r0 + s * i1;  im[i] = c * i0 - s * r1;
                    re[j] = s * i0 + c * r1;  im[j] = -s * r0 + c * i1;
                }
                // RY(w[ly][qq][1])
                th = w[(ly * 4 + qq) * 3 + 1] * 0.5f; c = __cosf(th); s = __sinf(th);
#pragma unroll
                for (int i = 0; i < 16; ++i) if (!(i & mm)) {
                    const int j = i | mm;
                    float r0 = re[i], i0 = im[i], r1 = re[j], i1 = im[j];
                    re[i] = c * r0 - s * r1;  im[i] = c * i0 - s * i1;
                    re[j] = s * r0 + c * r1;  im[j] = s * i0 + c * i1;
                }
                // RZ(w[ly][qq][2])
                th = w[(ly * 4 + qq) * 3 + 2] * 0.5f; c = __cosf(th); s = __sinf(th);
#pragma unroll
                for (int i = 0; i < 16; ++i) if (!(i & mm)) {
                    const int j = i | mm;
                    float r0 = re[i], i0 = im[i], r1 = re[j], i1 = im[j];
                    re[i] = c * r0 + s * i0;  im[i] = c * i0 - s * r0;
                    re[j] = c * r1 - s * i1;  im[j] = c * i1 + s * r1;
                }
            }
            // CNOT chain (q,q+1)
#pragma unroll
            for (int qq = 0; qq < 3; ++qq) {
                const int mc = 8 >> qq, mt = 8 >> (qq + 1);
#pragma unroll
                for (int i = 0; i < 16; ++i) if ((i & mc) && !(i & mt)) {
                    const int j = i | mt;
                    float tr = re[i]; re[i] = re[j]; re[j] = tr;
                    float ti = im[i]; im[i] = im[j]; im[j] = ti;
                }
            }
        }
#pragma unroll
        for (int k = 0; k < 16; ++k) { Ur[k][tid] = re[k]; Ui[k][tid] = im[k]; }
    }
    __syncthreads();

    // ---- step 2: M[j][l] = sum_k sign_q(k) Re(U[k,j] conj(U[k,l])) ----
    {
        const int j = tid >> 4, l = tid & 15;
        float acc = 0.0f;
#pragma unroll
        for (int k = 0; k < 16; ++k) {
            const float sgn = ((k >> (3 - q)) & 1) ? -1.0f : 1.0f;
            acc += sgn * (Ur[k][j] * Ur[k][l] + Ui[k][j] * Ui[k][l]);
        }
        M[j][l] = acc;
    }
    __syncthreads();

    // ---- step 3: project onto (1,cos,sin)^{(x)4} basis: 81 coeffs ----
    if (tid < 81) {
        int ap[4];
        ap[0] = tid / 27; ap[1] = (tid / 9) % 3; ap[2] = (tid / 3) % 3; ap[3] = tid % 3;
        float acc = 0.0f;
        for (int m = 0; m < 16; ++m) {
            int j = 0, l = 0; float sgn = 1.0f;
#pragma unroll
            for (int p = 0; p < 4; ++p) {
                const int o = (m >> (3 - p)) & 1;
                int jb = o, lb = (ap[p] == 2) ? (o ^ 1) : o;
                if (ap[p] == 1 && o) sgn = -sgn;
                j = (j << 1) | jb; l = (l << 1) | lb;
            }
            acc += sgn * M[j][l];
        }
        C[q * 81 + tid] = acc * 0.0625f;
    }
}

#define EPT 2

__global__ __launch_bounds__(256) void qmain(const float* __restrict__ x,
                                             const float* __restrict__ C,
                                             float* __restrict__ out, int B) {
    // ---- stage coefficients in LDS (uniform broadcast reads thereafter) ----
    __shared__ float sC[324];
    for (int i = threadIdx.x; i < 324; i += 256) sC[i] = C[i];
    __syncthreads();

    const int tid = blockIdx.x * 256 + threadIdx.x;
    const int total = gridDim.x * 256;

    // ---- loads + transcendentals for both elements up front (ILP) ----
    float cg[EPT][4], sg[EPT][4];
    bool valid[EPT];
#pragma unroll
    for (int k = 0; k < EPT; ++k) {
        const int b = tid + k * total;
        valid[k] = (b < B);
        float4 xv = make_float4(0.f, 0.f, 0.f, 0.f);
        if (valid[k]) xv = *reinterpret_cast<const float4*>(x + (size_t)b * 8);
        float xs[4] = {xv.x, xv.y, xv.z, xv.w};
#pragma unroll
        for (int q = 0; q < 4; ++q) {
            const float e = __expf(2.0f * xs[q]);
            const float t = 1.0f - __fdividef(2.0f, e + 1.0f);   // tanh(x)
            const float th = 3.1415f * t;
            cg[k][q] = __cosf(th);
            sg[k][q] = __sinf(th);
        }
    }

    // ---- polynomial eval: elements interleaved inside coefficient loop ----
    float ev[EPT][4];
#pragma unroll
    for (int q = 0; q < 4; ++q) {
        const float* __restrict__ Cq = sC + q * 81;
        float r27[EPT][27];
#pragma unroll
        for (int m = 0; m < 27; ++m) {
            const float c0 = Cq[3 * m], c1 = Cq[3 * m + 1], c2 = Cq[3 * m + 2];
#pragma unroll
            for (int k = 0; k < EPT; ++k)
                r27[k][m] = __fmaf_rn(c2, sg[k][3], __fmaf_rn(c1, cg[k][3], c0));
        }
        float r9[EPT][9];
#pragma unroll
        for (int m = 0; m < 9; ++m)
#pragma unroll
            for (int k = 0; k < EPT; ++k)
                r9[k][m] = __fmaf_rn(r27[k][3 * m + 2], sg[k][2],
                           __fmaf_rn(r27[k][3 * m + 1], cg[k][2], r27[k][3 * m]));
        float r3[EPT][3];
#pragma unroll
        for (int m = 0; m < 3; ++m)
#pragma unroll
            for (int k = 0; k < EPT; ++k)
                r3[k][m] = __fmaf_rn(r9[k][3 * m + 2], sg[k][1],
                           __fmaf_rn(r9[k][3 * m + 1], cg[k][1], r9[k][3 * m]));
#pragma unroll
        for (int k = 0; k < EPT; ++k)
            ev[k][q] = __fmaf_rn(r3[k][2], sg[k][0],
                       __fmaf_rn(r3[k][1], cg[k][0], r3[k][0]));
    }

#pragma unroll
    for (int k = 0; k < EPT; ++k) {
        const int b = tid + k * total;
        if (valid[k])
            *reinterpret_cast<float4*>(out + (size_t)b * 4) =
                make_float4(ev[k][0], ev[k][1], ev[k][2], ev[k][3]);
    }
}

extern "C" void kernel_launch(void* const* d_in, const int* in_sizes, int n_in,
                              void* d_out, int out_size, void* d_ws, size_t ws_size,
                              hipStream_t stream) {
    const float* x = (const float*)d_in[0];       // (B, 8) f32
    const float* w = (const float*)d_in[1];       // (2, 4, 3) f32
    float* out = (float*)d_out;                   // (B, 4) f32
    float* C = (float*)d_ws;                      // 4*81 floats scratch

    const int B = in_sizes[0] / 8;

    qsetup<<<4, 256, 0, stream>>>(w, C);

    const int threads_needed = (B + EPT - 1) / EPT;
    const int grid = (threads_needed + 255) / 256;
    qmain<<<grid, 256, 0, stream>>>(x, C, out, B);
}

// Round 4
// 25.306 us; speedup vs baseline: 1.7393x; 1.7393x over previous
//
#include <hip/hip_runtime.h>
#include <hip/hip_bf16.h>

// Quantum layer: 4 qubits, 2 layers. Everything after the RY(x) encoding is a
// fixed unitary U (weights are batch-constant). evs_q(x) = s^T Re(M_q) s with
// s the real product state from RY encoding; each output is multilinear in
// (1, cos th_p, sin th_p) per qubit: 81 coefficients per output.
// qsetup (4 blocks) computes C[4][81] from weights into d_ws.
// qmain: EPT=1, register-lean nested Horner; coefficients are wave-uniform
// constant-index loads -> scalar s_load path (no LDS, no vector loads).

__global__ __launch_bounds__(256) void qsetup(const float* __restrict__ w,
                                              float* __restrict__ C) {
    __shared__ float Ur[16][16];   // [row k][col j]
    __shared__ float Ui[16][16];
    __shared__ float M[16][16];
    const int q = blockIdx.x;      // output qubit 0..3
    const int tid = threadIdx.x;

    // ---- step 1: threads 0..15 each simulate one basis column of U ----
    if (tid < 16) {
        float re[16], im[16];
#pragma unroll
        for (int i = 0; i < 16; ++i) { re[i] = (i == tid) ? 1.0f : 0.0f; im[i] = 0.0f; }

#pragma unroll
        for (int ly = 0; ly < 2; ++ly) {
#pragma unroll
            for (int qq = 0; qq < 4; ++qq) {
                const int mm = 8 >> qq;
                float th, c, s;
                // RX(w[ly][qq][0])
                th = w[(ly * 4 + qq) * 3 + 0] * 0.5f; c = __cosf(th); s = __sinf(th);
#pragma unroll
                for (int i = 0; i < 16; ++i) if (!(i & mm)) {
                    const int j = i | mm;
                    float r0 = re[i], i0 = im[i], r1 = re[j], i1 = im[j];
                    re[i] = c * r0 + s * i1;  im[i] = c * i0 - s * r1;
                    re[j] = s * i0 + c * r1;  im[j] = -s * r0 + c * i1;
                }
                // RY(w[ly][qq][1])
                th = w[(ly * 4 + qq) * 3 + 1] * 0.5f; c = __cosf(th); s = __sinf(th);
#pragma unroll
                for (int i = 0; i < 16; ++i) if (!(i & mm)) {
                    const int j = i | mm;
                    float r0 = re[i], i0 = im[i], r1 = re[j], i1 = im[j];
                    re[i] = c * r0 - s * r1;  im[i] = c * i0 - s * i1;
                    re[j] = s * r0 + c * r1;  im[j] = s * i0 + c * i1;
                }
                // RZ(w[ly][qq][2])
                th = w[(ly * 4 + qq) * 3 + 2] * 0.5f; c = __cosf(th); s = __sinf(th);
#pragma unroll
                for (int i = 0; i < 16; ++i) if (!(i & mm)) {
                    const int j = i | mm;
                    float r0 = re[i], i0 = im[i], r1 = re[j], i1 = im[j];
                    re[i] = c * r0 + s * i0;  im[i] = c * i0 - s * r0;
                    re[j] = c * r1 - s * i1;  im[j] = c * i1 + s * r1;
                }
            }
            // CNOT chain (q,q+1)
#pragma unroll
            for (int qq = 0; qq < 3; ++qq) {
                const int mc = 8 >> qq, mt = 8 >> (qq + 1);
#pragma unroll
                for (int i = 0; i < 16; ++i) if ((i & mc) && !(i & mt)) {
                    const int j = i | mt;
                    float tr = re[i]; re[i] = re[j]; re[j] = tr;
                    float ti = im[i]; im[i] = im[j]; im[j] = ti;
                }
            }
        }
#pragma unroll
        for (int k = 0; k < 16; ++k) { Ur[k][tid] = re[k]; Ui[k][tid] = im[k]; }
    }
    __syncthreads();

    // ---- step 2: M[j][l] = sum_k sign_q(k) Re(U[k,j] conj(U[k,l])) ----
    {
        const int j = tid >> 4, l = tid & 15;
        float acc = 0.0f;
#pragma unroll
        for (int k = 0; k < 16; ++k) {
            const float sgn = ((k >> (3 - q)) & 1) ? -1.0f : 1.0f;
            acc += sgn * (Ur[k][j] * Ur[k][l] + Ui[k][j] * Ui[k][l]);
        }
        M[j][l] = acc;
    }
    __syncthreads();

    // ---- step 3: project onto (1,cos,sin)^{(x)4} basis: 81 coeffs ----
    if (tid < 81) {
        int ap[4];
        ap[0] = tid / 27; ap[1] = (tid / 9) % 3; ap[2] = (tid / 3) % 3; ap[3] = tid % 3;
        float acc = 0.0f;
        for (int m = 0; m < 16; ++m) {
            int j = 0, l = 0; float sgn = 1.0f;
#pragma unroll
            for (int p = 0; p < 4; ++p) {
                const int o = (m >> (3 - p)) & 1;
                int jb = o, lb = (ap[p] == 2) ? (o ^ 1) : o;
                if (ap[p] == 1 && o) sgn = -sgn;
                j = (j << 1) | jb; l = (l << 1) | lb;
            }
            acc += sgn * M[j][l];
        }
        C[q * 81 + tid] = acc * 0.0625f;
    }
}

__global__ __launch_bounds__(256) void qmain(const float* __restrict__ x,
                                             const float* __restrict__ C,
                                             float* __restrict__ out, int B) {
    const int b = blockIdx.x * 256 + threadIdx.x;
    if (b >= B) return;

    const float4 xv = *reinterpret_cast<const float4*>(x + (size_t)b * 8);
    float c0, s0, c1, s1, c2, s2, c3, s3;
    {
        float xs[4] = {xv.x, xv.y, xv.z, xv.w};
        float cc[4], ss[4];
#pragma unroll
        for (int q = 0; q < 4; ++q) {
            const float e = __expf(2.0f * xs[q]);
            const float t = 1.0f - __fdividef(2.0f, e + 1.0f);   // tanh(x)
            __sincosf(3.1415f * t, &ss[q], &cc[q]);
        }
        c0 = cc[0]; s0 = ss[0]; c1 = cc[1]; s1 = ss[1];
        c2 = cc[2]; s2 = ss[2]; c3 = cc[3]; s3 = ss[3];
    }

    // Nested Horner over the (1,c,s)^(x)4 basis; ~6 live temps, coefficients
    // are uniform constant-index loads (scalar path).
    float ev[4];
#pragma unroll
    for (int q = 0; q < 4; ++q) {
        const float* __restrict__ Cq = C + q * 81;
        float acc = 0.0f;
#pragma unroll
        for (int i = 0; i < 3; ++i) {
            float ai = 0.0f;
#pragma unroll
            for (int j = 0; j < 3; ++j) {
                float aj = 0.0f;
#pragma unroll
                for (int k = 0; k < 3; ++k) {
                    const float* cp = Cq + ((i * 3 + j) * 3 + k) * 3;
                    const float t = __fmaf_rn(cp[2], s3, __fmaf_rn(cp[1], c3, cp[0]));
                    if (k == 0)      aj = t;
                    else if (k == 1) aj = __fmaf_rn(t, c2, aj);
                    else             aj = __fmaf_rn(t, s2, aj);
                }
                if (j == 0)      ai = aj;
                else if (j == 1) ai = __fmaf_rn(aj, c1, ai);
                else             ai = __fmaf_rn(aj, s1, ai);
            }
            if (i == 0)      acc = ai;
            else if (i == 1) acc = __fmaf_rn(ai, c0, acc);
            else             acc = __fmaf_rn(ai, s0, acc);
        }
        ev[q] = acc;
    }

    *reinterpret_cast<float4*>(out + (size_t)b * 4) = make_float4(ev[0], ev[1], ev[2], ev[3]);
}

extern "C" void kernel_launch(void* const* d_in, const int* in_sizes, int n_in,
                              void* d_out, int out_size, void* d_ws, size_t ws_size,
                              hipStream_t stream) {
    const float* x = (const float*)d_in[0];       // (B, 8) f32
    const float* w = (const float*)d_in[1];       // (2, 4, 3) f32
    float* out = (float*)d_out;                   // (B, 4) f32
    float* C = (float*)d_ws;                      // 4*81 floats scratch

    const int B = in_sizes[0] / 8;

    qsetup<<<4, 256, 0, stream>>>(w, C);
    qmain<<<(B + 255) / 256, 256, 0, stream>>>(x, C, out, B);
}